// Round 5
// baseline (434.904 us; speedup 1.0000x reference)
//
#include <hip/hip_runtime.h>

typedef unsigned short u16;
typedef unsigned int u32;
typedef __bf16 bf16x8 __attribute__((ext_vector_type(8)));
typedef _Float16 f16x8 __attribute__((ext_vector_type(8)));
typedef __fp16 fp16x2 __attribute__((ext_vector_type(2)));
typedef float f32x4 __attribute__((ext_vector_type(4)));

__device__ __forceinline__ u16 f2b(float f) {
  u32 u = __float_as_uint(f);
  return (u16)((u + 0x7FFFu + ((u >> 16) & 1u)) >> 16);
}
__device__ __forceinline__ u16 f2h(float f) {
  union { _Float16 h; u16 u; } c;
  c.h = (_Float16)f;
  return c.u;
}
__device__ __forceinline__ u32 pk2h(float a, float b) {
  union { fp16x2 v; u32 u; } c;
  c.v = __builtin_amdgcn_cvt_pkrtz(a, b);
  return c.u;
}
__device__ __forceinline__ float sumsq2(u32 u) {  // bf16 pair
  float lo = __uint_as_float(u << 16);
  float hi = __uint_as_float(u & 0xFFFF0000u);
  return lo * lo + hi * hi;
}
__device__ __forceinline__ void gl2lds16(const void* g, void* l) {
  __builtin_amdgcn_global_load_lds((__attribute__((address_space(1))) void*)g,
                                   (__attribute__((address_space(3))) void*)l, 16, 0, 0);
}

// ---------- fused fp32 -> bf16 transposed weights (all 6 in one launch) ----------
struct W6 {
  const float* src[6];
  u16* dst[6];
};
__global__ __launch_bounds__(256) void k_wtrans6(W6 p) {
  const float* __restrict__ W = p.src[blockIdx.z];
  u16* __restrict__ Wt = p.dst[blockIdx.z];
  __shared__ float sm[64 * 65];
  const int r0 = blockIdx.y * 64, c0 = blockIdx.x * 64;
  const int tid = threadIdx.x;
#pragma unroll
  for (int i = 0; i < 16; ++i) {
    int idx = i * 256 + tid;
    int r = idx >> 6, c = idx & 63;
    sm[c * 65 + r] = W[(size_t)(r0 + r) * 1024 + c0 + c];
  }
  __syncthreads();
#pragma unroll
  for (int i = 0; i < 16; ++i) {
    int idx = i * 256 + tid;
    int r = idx >> 6, c = idx & 63;
    Wt[(size_t)(c0 + r) * 1024 + r0 + c] = f2b(sm[r * 65 + c]);
  }
}

// ---------- layernorm fp32 -> bf16 ----------
__global__ __launch_bounds__(256) void k_ln(const float* __restrict__ x,
                                            const float* __restrict__ w,
                                            const float* __restrict__ bb,
                                            u16* __restrict__ y) {
  const int row = blockIdx.x;
  const int tid = threadIdx.x;
  const float4 v = ((const float4*)(x + (size_t)row * 1024))[tid];
  float s = v.x + v.y + v.z + v.w;
  float s2 = v.x * v.x + v.y * v.y + v.z * v.z + v.w * v.w;
  for (int o = 32; o > 0; o >>= 1) {
    s += __shfl_down(s, o);
    s2 += __shfl_down(s2, o);
  }
  __shared__ float red[8];
  const int wave = tid >> 6;
  if ((tid & 63) == 0) { red[wave * 2] = s; red[wave * 2 + 1] = s2; }
  __syncthreads();
  s = red[0] + red[2] + red[4] + red[6];
  s2 = red[1] + red[3] + red[5] + red[7];
  const float mu = s * (1.0f / 1024.0f);
  const float var = s2 * (1.0f / 1024.0f) - mu * mu;
  const float rs = rsqrtf(var + 1e-5f);
  const float4 wv = ((const float4*)w)[tid];
  const float4 bv = ((const float4*)bb)[tid];
  u16* yr = y + (size_t)row * 1024 + tid * 4;
  yr[0] = f2b((v.x - mu) * rs * wv.x + bv.x);
  yr[1] = f2b((v.y - mu) * rs * wv.y + bv.y);
  yr[2] = f2b((v.z - mu) * rs * wv.z + bv.z);
  yr[3] = f2b((v.w - mu) * rs * wv.w + bv.w);
}

// ---------- per-head sum of squares of qk rows (token path, bf16 input) ----------
__global__ __launch_bounds__(256) void k_q2(const u16* __restrict__ qk,
                                            float* __restrict__ q2) {
  const int row = blockIdx.x * 4 + (threadIdx.x >> 6);
  const int lane = threadIdx.x & 63;
  const u16* p = qk + (size_t)row * 1024 + lane * 16;
  const uint4 a = *(const uint4*)p;
  const uint4 b = *(const uint4*)(p + 8);
  float s = sumsq2(a.x) + sumsq2(a.y) + sumsq2(a.z) + sumsq2(a.w) +
            sumsq2(b.x) + sumsq2(b.y) + sumsq2(b.z) + sumsq2(b.w);
  s += __shfl_down(s, 1, 4);
  s += __shfl_down(s, 2, 4);
  if ((lane & 3) == 0) {
    const int h = lane >> 2;
    const int bidx = row >> 10, n = row & 1023;
    q2[((size_t)(bidx * 16 + h)) * 1024 + n] = s;
  }
}

// ---------- 128x128-tile bf16 MFMA GEMM core (B^T layout, m97 structure) ----------
__device__ __forceinline__ void gemm_core_128(const u16* __restrict__ Ab,
                                              const u16* __restrict__ Bb,
                                              int lda, int ldb, int K,
                                              u16* sm, f32x4 acc[4][4]) {
  const int tid = threadIdx.x;
  const int wave = tid >> 6;
  const int wr = wave >> 1, wc = wave & 1;
  const int lane = tid & 63;
  const int lc = lane & 15, quad = lane >> 4;
  u16* smA = sm;
  u16* smB = sm + 4096;
  const int sr = tid >> 2, sk = (tid & 3) << 3;
  const u16* gA = Ab + (size_t)sr * lda + sk;
  const u16* gB = Bb + (size_t)sr * ldb + sk;
  const size_t a64 = (size_t)64 * lda, b64 = (size_t)64 * ldb;
  u16* dA = smA + tid * 8;
  u16* dB = smB + tid * 8;
  for (int kt = 0; kt < K; kt += 32) {
    gl2lds16(gA + kt, dA);
    gl2lds16(gA + a64 + kt, dA + 2048);
    gl2lds16(gB + kt, dB);
    gl2lds16(gB + b64 + kt, dB + 2048);
    __syncthreads();
    bf16x8 af[4], bfr[4];
#pragma unroll
    for (int i = 0; i < 4; ++i) {
      af[i] = *(const bf16x8*)(smA + (wr * 64 + i * 16 + lc) * 32 + quad * 8);
      bfr[i] = *(const bf16x8*)(smB + (wc * 64 + i * 16 + lc) * 32 + quad * 8);
    }
#pragma unroll
    for (int i = 0; i < 4; ++i)
#pragma unroll
      for (int j = 0; j < 4; ++j)
        acc[i][j] = __builtin_amdgcn_mfma_f32_16x16x32_bf16(af[i], bfr[j], acc[i][j], 0, 0, 0);
    __syncthreads();
  }
}

// ---------- fused dual GEMM: z=0 -> row-major bf16 C; z=1 -> per-batch-transposed f16 ----------
__global__ __launch_bounds__(256) void k_gemm_nt(const u16* __restrict__ A,
                                                 const u16* __restrict__ Btn,
                                                 const u16* __restrict__ Btt,
                                                 u16* __restrict__ Cn,
                                                 u16* __restrict__ CtT) {
  __shared__ u16 sm[8704];
  const int m0 = blockIdx.x * 128, n0 = blockIdx.y * 128;
  const u16* Bt = (blockIdx.z == 0) ? Btn : Btt;
  f32x4 acc[4][4];
#pragma unroll
  for (int i = 0; i < 4; ++i)
#pragma unroll
    for (int j = 0; j < 4; ++j) acc[i][j] = (f32x4){0.f, 0.f, 0.f, 0.f};
  gemm_core_128(A + (size_t)m0 * 1024, Bt + (size_t)n0 * 1024, 1024, 1024, 1024, sm, acc);
  const int tid = threadIdx.x, wave = tid >> 6;
  const int wr = wave >> 1, wc = wave & 1;
  const int lc = tid & 15, quad = (tid & 63) >> 4;
  if (blockIdx.z == 0) {
#pragma unroll
    for (int i = 0; i < 4; ++i)
#pragma unroll
      for (int j = 0; j < 4; ++j) {
        const int n = n0 + wc * 64 + j * 16 + lc;
#pragma unroll
        for (int r = 0; r < 4; ++r) {
          const int m = m0 + wr * 64 + i * 16 + quad * 4 + r;
          Cn[(size_t)m * 1024 + n] = f2b(acc[i][j][r]);
        }
      }
  } else {
    const int b = m0 >> 10, mloc = m0 & 1023;
    for (int half = 0; half < 2; ++half) {
      if (wc == half) {
#pragma unroll
        for (int i = 0; i < 4; ++i)
#pragma unroll
          for (int j = 0; j < 4; ++j)
#pragma unroll
            for (int r = 0; r < 4; ++r)
              sm[(j * 16 + lc) * 136 + wr * 64 + i * 16 + quad * 4 + r] = f2h(acc[i][j][r]);
      }
      __syncthreads();
#pragma unroll
      for (int it = 0; it < 4; ++it) {
        const int rr = it * 16 + (tid >> 4);
        const int c8 = (tid & 15) << 3;
        *(uint4*)&CtT[((size_t)(b * 1024 + n0 + half * 64 + rr)) * 1024 + mloc + c8] =
            *(const uint4*)&sm[rr * 136 + c8];
      }
      __syncthreads();
    }
  }
}

// ---------- GEMM + residual epilogue: out = res + acc*gamma[n] (fp32) ----------
__global__ __launch_bounds__(256) void k_gemm_res(const u16* __restrict__ A,
                                                  const u16* __restrict__ Bt,
                                                  const float* __restrict__ res,
                                                  const float* __restrict__ gamma,
                                                  float* __restrict__ out) {
  __shared__ u16 sm[8192];
  const int m0 = blockIdx.x * 128, n0 = blockIdx.y * 128;
  f32x4 acc[4][4];
#pragma unroll
  for (int i = 0; i < 4; ++i)
#pragma unroll
    for (int j = 0; j < 4; ++j) acc[i][j] = (f32x4){0.f, 0.f, 0.f, 0.f};
  gemm_core_128(A + (size_t)m0 * 1024, Bt + (size_t)n0 * 1024, 1024, 1024, 1024, sm, acc);
  const int tid = threadIdx.x, wave = tid >> 6;
  const int wr = wave >> 1, wc = wave & 1;
  const int lc = tid & 15, quad = (tid & 63) >> 4;
#pragma unroll
  for (int i = 0; i < 4; ++i)
#pragma unroll
    for (int j = 0; j < 4; ++j) {
      const int n = n0 + wc * 64 + j * 16 + lc;
      const float g = gamma[n];
#pragma unroll
      for (int r = 0; r < 4; ++r) {
        const size_t idx = (size_t)(m0 + wr * 64 + i * 16 + quad * 4 + r) * 1024 + n;
        out[idx] = res[idx] + acc[i][j][r] * g;
      }
    }
}

// ---------- token attention: 8 waves, q-tile 128, Q staged through sP, 35.3KB LDS ----------
// grid: 1024 1-D blocks, id = qt*128 + bh -> XCD = bh%8; 4 blocks/CU = 32 waves/CU,
// 1024 blocks = exactly one full residency round (4 x 256 CUs).
__global__ __launch_bounds__(512, 8) void k_attn(const u16* __restrict__ qk,   // bf16
                                                 const u16* __restrict__ vT,   // f16 (B,D,N)
                                                 const float* __restrict__ q2,
                                                 const float* __restrict__ tau,
                                                 u16* __restrict__ outp) {
  const int bh = blockIdx.x & 127;
  const int q0 = (blockIdx.x >> 7) * 128;
  const int b = bh >> 4, h = bh & 15;
  __shared__ u16 sK[4096];      // [64 k][64 d] bf16, swizzled chunks (8 KB)
  __shared__ u16 sV[4096];      // [64 d][64 n] f16,  swizzled chunks (8 KB)
  __shared__ u16 sP[128 * 72];  // P [q][k] f16 padded (18 KB); transiently holds Q tile
  __shared__ float sInv[128];
  const int tid = threadIdx.x;   // 0..511
  const int wave = tid >> 6;     // 0..7
  const int lane = tid & 63;
  const int lc = lane & 15, quad = lane >> 4;
  const int sw = lc & 7;         // xor swizzle key for fragment reads
  const float scale = tau[h] * 0.125f;  // 1/sqrt(64)
  const float two_scale = 2.0f * scale;
  const u16* qkb = qk + (size_t)b * (1024 * 1024) + h * 64;
  const u16* vTb = vT + ((size_t)b * 1024 + h * 64) * 1024;
  const float* q2g = q2 + (size_t)bh * 1024;

  // staging pattern: 512 threads, 1 16B chunk each covers a 64x64 tile
  const int r0 = tid >> 3;                    // 0..63
  const int c0s = (tid & 7) ^ (r0 & 7);       // swizzled col chunk

  // stage Q tile (128 rows) into sP region (transient)
  gl2lds16(qkb + (size_t)(q0 + r0) * 1024 + c0s * 8, sP + tid * 8);
  gl2lds16(qkb + (size_t)(q0 + 64 + r0) * 1024 + c0s * 8, sP + 4096 + tid * 8);
  __syncthreads();  // Q landed

  const int qr = wave * 16 + lc;  // this wave's q row (qr&7 == lc&7)
  const bf16x8 aq0 = *(const bf16x8*)(sP + (qr * 8 + (quad ^ sw)) * 8);
  const bf16x8 aq1 = *(const bf16x8*)(sP + (qr * 8 + ((4 + quad) ^ sw)) * 8);
  const float tq = q2g[q0 + qr] * scale;

  f32x4 oacc[4];
#pragma unroll
  for (int j = 0; j < 4; ++j) oacc[j] = (f32x4){0.f, 0.f, 0.f, 0.f};
  float rsum = 0.f;

  for (int kt = 0; kt < 16; ++kt) {
    __syncthreads();  // (A) prev iter's sK/sV reads done; iter0: aq reads done
    const int kbase = kt * 64;
    gl2lds16(qkb + (size_t)(kbase + r0) * 1024 + c0s * 8, sK + tid * 8);
    gl2lds16(vTb + (size_t)r0 * 1024 + kbase + c0s * 8, sV + tid * 8);
    __syncthreads();  // (B) K/V landed

    // fused S^T = K*Q^T + exp per 16-k block (keeps f32x4 liveness minimal)
#pragma unroll
    for (int nb = 0; nb < 4; ++nb) {
      const int krow = nb * 16 + lc;
      const bf16x8 bk0 = *(const bf16x8*)(sK + (krow * 8 + (quad ^ sw)) * 8);
      const bf16x8 bk1 = *(const bf16x8*)(sK + (krow * 8 + ((4 + quad) ^ sw)) * 8);
      f32x4 z = (f32x4){0.f, 0.f, 0.f, 0.f};
      z = __builtin_amdgcn_mfma_f32_16x16x32_bf16(bk0, aq0, z, 0, 0, 0);
      z = __builtin_amdgcn_mfma_f32_16x16x32_bf16(bk1, aq1, z, 0, 0, 0);
      const float4 tk4 = *(const float4*)(q2g + kbase + nb * 16 + quad * 4);
      const float e0 = __expf(fmaf(z[0], two_scale, -fmaf(tk4.x, scale, tq)));
      const float e1 = __expf(fmaf(z[1], two_scale, -fmaf(tk4.y, scale, tq)));
      const float e2 = __expf(fmaf(z[2], two_scale, -fmaf(tk4.z, scale, tq)));
      const float e3 = __expf(fmaf(z[3], two_scale, -fmaf(tk4.w, scale, tq)));
      *(uint2*)&sP[qr * 72 + nb * 16 + quad * 4] = make_uint2(pk2h(e0, e1), pk2h(e2, e3));
      rsum += (e0 + e1) + (e2 + e3);
    }
    // P * V (A = own P rows, B = V^T rows); sP rows are wave-local, lgkmcnt only
    const f16x8 ap0 = *(const f16x8*)&sP[qr * 72 + quad * 8];
    const f16x8 ap1 = *(const f16x8*)&sP[qr * 72 + 32 + quad * 8];
#pragma unroll
    for (int j2 = 0; j2 < 4; ++j2) {
      const int drow = j2 * 16 + lc;
      const f16x8 bv0 = *(const f16x8*)(sV + (drow * 8 + (quad ^ sw)) * 8);
      const f16x8 bv1 = *(const f16x8*)(sV + (drow * 8 + ((4 + quad) ^ sw)) * 8);
      oacc[j2] = __builtin_amdgcn_mfma_f32_16x16x32_f16(ap0, bv0, oacc[j2], 0, 0, 0);
      oacc[j2] = __builtin_amdgcn_mfma_f32_16x16x32_f16(ap1, bv1, oacc[j2], 0, 0, 0);
    }
  }
  // row sums: reduce across quads (k partitions), distribute via wave-local LDS
  rsum += __shfl_xor(rsum, 16);
  rsum += __shfl_xor(rsum, 32);
  if (lane < 16) sInv[wave * 16 + lane] = 1.f / rsum;
#pragma unroll
  for (int r = 0; r < 4; ++r) {
    const int row = wave * 16 + quad * 4 + r;
    const float inv = sInv[row];
    u16* o = outp + ((size_t)(b * 1024 + q0 + row)) * 1024 + h * 64;
#pragma unroll
    for (int j2 = 0; j2 < 4; ++j2) o[j2 * 16 + lc] = f2b(oacc[j2][r] * inv);
  }
}

// ---------- channel attention matrix: softmax(scaled X^T X); diag(Gram) = q2 fused ----------
__global__ __launch_bounds__(256) void k_chan_s(const u16* __restrict__ qkcT,  // f16
                                                const float* __restrict__ tau,
                                                u16* __restrict__ Aout) {      // bf16
  const int bc = blockIdx.x, b = bc >> 3, c = bc & 7;
  __shared__ u16 sX[8192];
  __shared__ float sq2[128];
  const int tid = threadIdx.x, wave = tid >> 6, lane = tid & 63;
  const int lc = lane & 15, quad = lane >> 4;
  const u16* Xb = qkcT + ((size_t)b * 1024 + c * 128) * 1024;
  f32x4 acc[2][8];
#pragma unroll
  for (int i = 0; i < 2; ++i)
#pragma unroll
    for (int j = 0; j < 8; ++j) acc[i][j] = (f32x4){0.f, 0.f, 0.f, 0.f};
  for (int nt = 0; nt < 1024; nt += 64) {
#pragma unroll
    for (int i = 0; i < 4; ++i) {
      const int idx = i * 256 + tid;
      gl2lds16(Xb + (size_t)(idx >> 3) * 1024 + nt + ((idx & 7) << 3), sX + idx * 8);
    }
    __syncthreads();
    f16x8 af[2][2];
#pragma unroll
    for (int i = 0; i < 2; ++i)
#pragma unroll
      for (int ks = 0; ks < 2; ++ks)
        af[i][ks] =
            *(const f16x8*)&sX[((wave * 2 + i) * 16 + lc) * 64 + ks * 32 + quad * 8];
#pragma unroll
    for (int nb = 0; nb < 8; ++nb)
#pragma unroll
      for (int ks = 0; ks < 2; ++ks) {
        const f16x8 bb = *(const f16x8*)&sX[(nb * 16 + lc) * 64 + ks * 32 + quad * 8];
        acc[0][nb] = __builtin_amdgcn_mfma_f32_16x16x32_f16(af[0][ks], bb, acc[0][nb], 0, 0, 0);
        acc[1][nb] = __builtin_amdgcn_mfma_f32_16x16x32_f16(af[1][ks], bb, acc[1][nb], 0, 0, 0);
      }
    __syncthreads();
  }
  // extract Gram diagonal -> sq2 (row == col when lc>>2 == quad, nb == wave*2+i)
#pragma unroll
  for (int i = 0; i < 2; ++i) {
    const int nbd = wave * 2 + i;
    if ((lc >> 2) == quad) sq2[nbd * 16 + lc] = acc[i][nbd][lc & 3];
  }
  __syncthreads();
  const float scl = tau[c] * (1.f / 32.f);  // 1/sqrt(1024)
#pragma unroll
  for (int i = 0; i < 2; ++i) {
    const int rbase = (wave * 2 + i) * 16 + quad * 4;
#pragma unroll
    for (int r = 0; r < 4; ++r) {
      const float q2r = sq2[rbase + r];
      float ee[8];
      float ps = 0.f;
#pragma unroll
      for (int nb = 0; nb < 8; ++nb) {
        const float e = __expf((2.f * acc[i][nb][r] - q2r - sq2[nb * 16 + lc]) * scl);
        ee[nb] = e;
        ps += e;
      }
      ps += __shfl_xor(ps, 1);
      ps += __shfl_xor(ps, 2);
      ps += __shfl_xor(ps, 4);
      ps += __shfl_xor(ps, 8);
      const float inv = 1.f / ps;
      u16* Ao = Aout + (size_t)bc * 16384 + (size_t)(rbase + r) * 128;
#pragma unroll
      for (int nb = 0; nb < 8; ++nb) Ao[nb * 16 + lc] = f2b(ee[nb] * inv);
    }
  }
}

// ---------- channel PV: out[b,n,c*128+d] = sum_d' vc[b,n,c*128+d'] * A[d][d'] ----------
__global__ __launch_bounds__(256) void k_chan_pv(const u16* __restrict__ vc,
                                                 const u16* __restrict__ Ac,
                                                 u16* __restrict__ outp) {
  __shared__ u16 sm[8192];
  const int bc = blockIdx.y, b = bc >> 3, c = bc & 7;
  const int m0 = blockIdx.x * 128;
  f32x4 acc[4][4];
#pragma unroll
  for (int i = 0; i < 4; ++i)
#pragma unroll
    for (int j = 0; j < 4; ++j) acc[i][j] = (f32x4){0.f, 0.f, 0.f, 0.f};
  gemm_core_128(vc + ((size_t)b * 1024 + m0) * 1024 + c * 128, Ac + (size_t)bc * 16384,
                1024, 128, 128, sm, acc);
  const int tid = threadIdx.x, wave = tid >> 6;
  const int wr = wave >> 1, wc = wave & 1;
  const int lc = tid & 15, quad = (tid & 63) >> 4;
#pragma unroll
  for (int i = 0; i < 4; ++i)
#pragma unroll
    for (int j = 0; j < 4; ++j)
#pragma unroll
      for (int r = 0; r < 4; ++r)
        outp[((size_t)(b * 1024 + m0 + wr * 64 + i * 16 + quad * 4 + r)) * 1024 + c * 128 +
             wc * 64 + j * 16 + lc] = f2b(acc[i][j][r]);
}

extern "C" void kernel_launch(void* const* d_in, const int* in_sizes, int n_in,
                              void* d_out, int out_size, void* d_ws, size_t ws_size,
                              hipStream_t stream) {
  (void)in_sizes; (void)n_in; (void)out_size; (void)ws_size;
  const float* x = (const float*)d_in[0];
  const float* tau_t = (const float*)d_in[4];
  const float* tau_c = (const float*)d_in[8];
  const float* ln1w = (const float*)d_in[9];
  const float* ln1b = (const float*)d_in[10];
  const float* ln2w = (const float*)d_in[11];
  const float* ln2b = (const float*)d_in[12];
  const float* g1 = (const float*)d_in[13];
  const float* g2 = (const float*)d_in[14];
  float* out = (float*)d_out;

  // workspace carve-up
  char* p = (char*)d_ws;
  u16* wb[6];
  for (int i = 0; i < 6; ++i) wb[i] = (u16*)(p + (size_t)i * (2u << 20));
  u16* bufA = (u16*)(p + (size_t)12 * (1u << 20));       // 16 MB
  u16* bufQ = bufA + (size_t)8 * 1024 * 1024;            // 16 MB
  u16* bufV = bufQ + (size_t)8 * 1024 * 1024;            // 16 MB
  float* q2b = (float*)(bufV + (size_t)8 * 1024 * 1024); // 512 KB
  u16* Ac = (u16*)(q2b + 131072 + 8192);                 // 2 MB

  W6 w6;
  const int widx[6] = {1, 2, 3, 5, 6, 7};  // Wqk_t, Wv_t, Wo_t, Wqk_c, Wv_c, Wo_c
  for (int i = 0; i < 6; ++i) { w6.src[i] = (const float*)d_in[widx[i]]; w6.dst[i] = wb[i]; }
  k_wtrans6<<<dim3(16, 16, 6), 256, 0, stream>>>(w6);

  // ---- token diffusion ----
  k_ln<<<8192, 256, 0, stream>>>(x, ln1w, ln1b, bufA);                           // y1 (bf16)
  k_gemm_nt<<<dim3(64, 8, 2), 256, 0, stream>>>(bufA, wb[0], wb[1], bufQ, bufV); // qk bf16 + v^T f16
  k_q2<<<2048, 256, 0, stream>>>(bufQ, q2b);
  k_attn<<<1024, 512, 0, stream>>>(bufQ, bufV, q2b, tau_t, bufA);                // attn_out bf16
  k_gemm_res<<<dim3(64, 8), 256, 0, stream>>>(bufA, wb[2], x, g1, out);          // x1 = x + Wo*g1

  // ---- channel diffusion ----
  k_ln<<<8192, 256, 0, stream>>>(out, ln2w, ln2b, bufQ);                         // y2 (bf16)
  k_gemm_nt<<<dim3(64, 8, 2), 256, 0, stream>>>(bufQ, wb[4], wb[3], bufA, bufV); // vc bf16 + qkc^T f16
  k_chan_s<<<64, 256, 0, stream>>>(bufV, tau_c, Ac);                             // softmax matrix (diag fused)
  k_chan_pv<<<dim3(8, 64), 256, 0, stream>>>(bufA, Ac, bufQ);                    // chan attn out bf16
  k_gemm_res<<<dim3(64, 8), 256, 0, stream>>>(bufQ, wb[5], out, g2, out);        // out = x1 + Wo*g2
}

// Round 6
// 401.570 us; speedup vs baseline: 1.0830x; 1.0830x over previous
//
#include <hip/hip_runtime.h>

typedef unsigned short u16;
typedef unsigned int u32;
typedef __bf16 bf16x8 __attribute__((ext_vector_type(8)));
typedef _Float16 f16x8 __attribute__((ext_vector_type(8)));
typedef __fp16 fp16x2 __attribute__((ext_vector_type(2)));
typedef float f32x4 __attribute__((ext_vector_type(4)));

__device__ __forceinline__ u16 f2b(float f) {
  u32 u = __float_as_uint(f);
  return (u16)((u + 0x7FFFu + ((u >> 16) & 1u)) >> 16);
}
__device__ __forceinline__ u16 f2h(float f) {
  union { _Float16 h; u16 u; } c;
  c.h = (_Float16)f;
  return c.u;
}
__device__ __forceinline__ u32 pk2h(float a, float b) {
  union { fp16x2 v; u32 u; } c;
  c.v = __builtin_amdgcn_cvt_pkrtz(a, b);
  return c.u;
}
__device__ __forceinline__ float sumsq2(u32 u) {  // bf16 pair
  float lo = __uint_as_float(u << 16);
  float hi = __uint_as_float(u & 0xFFFF0000u);
  return lo * lo + hi * hi;
}
__device__ __forceinline__ void gl2lds16(const void* g, void* l) {
  __builtin_amdgcn_global_load_lds((__attribute__((address_space(1))) void*)g,
                                   (__attribute__((address_space(3))) void*)l, 16, 0, 0);
}

// ---------- fused fp32 -> bf16 transposed weights (all 6 in one launch) ----------
struct W6 {
  const float* src[6];
  u16* dst[6];
};
__global__ __launch_bounds__(256) void k_wtrans6(W6 p) {
  const float* __restrict__ W = p.src[blockIdx.z];
  u16* __restrict__ Wt = p.dst[blockIdx.z];
  __shared__ float sm[64 * 65];
  const int r0 = blockIdx.y * 64, c0 = blockIdx.x * 64;
  const int tid = threadIdx.x;
#pragma unroll
  for (int i = 0; i < 16; ++i) {
    int idx = i * 256 + tid;
    int r = idx >> 6, c = idx & 63;
    sm[c * 65 + r] = W[(size_t)(r0 + r) * 1024 + c0 + c];
  }
  __syncthreads();
#pragma unroll
  for (int i = 0; i < 16; ++i) {
    int idx = i * 256 + tid;
    int r = idx >> 6, c = idx & 63;
    Wt[(size_t)(c0 + r) * 1024 + r0 + c] = f2b(sm[r * 65 + c]);
  }
}

// ---------- layernorm fp32 -> bf16 ----------
__global__ __launch_bounds__(256) void k_ln(const float* __restrict__ x,
                                            const float* __restrict__ w,
                                            const float* __restrict__ bb,
                                            u16* __restrict__ y) {
  const int row = blockIdx.x;
  const int tid = threadIdx.x;
  const float4 v = ((const float4*)(x + (size_t)row * 1024))[tid];
  float s = v.x + v.y + v.z + v.w;
  float s2 = v.x * v.x + v.y * v.y + v.z * v.z + v.w * v.w;
  for (int o = 32; o > 0; o >>= 1) {
    s += __shfl_down(s, o);
    s2 += __shfl_down(s2, o);
  }
  __shared__ float red[8];
  const int wave = tid >> 6;
  if ((tid & 63) == 0) { red[wave * 2] = s; red[wave * 2 + 1] = s2; }
  __syncthreads();
  s = red[0] + red[2] + red[4] + red[6];
  s2 = red[1] + red[3] + red[5] + red[7];
  const float mu = s * (1.0f / 1024.0f);
  const float var = s2 * (1.0f / 1024.0f) - mu * mu;
  const float rs = rsqrtf(var + 1e-5f);
  const float4 wv = ((const float4*)w)[tid];
  const float4 bv = ((const float4*)bb)[tid];
  u16* yr = y + (size_t)row * 1024 + tid * 4;
  yr[0] = f2b((v.x - mu) * rs * wv.x + bv.x);
  yr[1] = f2b((v.y - mu) * rs * wv.y + bv.y);
  yr[2] = f2b((v.z - mu) * rs * wv.z + bv.z);
  yr[3] = f2b((v.w - mu) * rs * wv.w + bv.w);
}

// ---------- 128x128-tile bf16 MFMA GEMM core, BK=64 (two 32-k sub-tiles/barrier) ----------
// LDS: smA = sm[0..8191] (two [128][32] subs), smB = sm[8192..16383]. 32 KB.
__device__ __forceinline__ void gemm_core_bk64(const u16* __restrict__ Ab,
                                               const u16* __restrict__ Bb,
                                               int lda, int ldb, int K,
                                               u16* sm, f32x4 acc[4][4]) {
  const int tid = threadIdx.x;
  const int wave = tid >> 6;
  const int wr = wave >> 1, wc = wave & 1;
  const int lane = tid & 63;
  const int lc = lane & 15, quad = lane >> 4;
  u16* smA = sm;
  u16* smB = sm + 8192;
  const int sr = tid >> 2, sk = (tid & 3) << 3;  // row 0..63, k-chunk
  const u16* gA = Ab + (size_t)sr * lda + sk;
  const u16* gB = Bb + (size_t)sr * ldb + sk;
  const size_t a64 = (size_t)64 * lda, b64 = (size_t)64 * ldb;
  // dest byte offset = tid*16 within each (sub, row-half) region -> wave-uniform+lane*16 OK
  u16* dA = smA + tid * 8;
  u16* dB = smB + tid * 8;
  for (int kt = 0; kt < K; kt += 64) {
    // sub 0 (k: kt..kt+31)
    gl2lds16(gA + kt, dA);
    gl2lds16(gA + a64 + kt, dA + 2048);
    gl2lds16(gB + kt, dB);
    gl2lds16(gB + b64 + kt, dB + 2048);
    // sub 1 (k: kt+32..kt+63)
    gl2lds16(gA + kt + 32, dA + 4096);
    gl2lds16(gA + a64 + kt + 32, dA + 6144);
    gl2lds16(gB + kt + 32, dB + 4096);
    gl2lds16(gB + b64 + kt + 32, dB + 6144);
    __syncthreads();
#pragma unroll
    for (int ks = 0; ks < 2; ++ks) {
      bf16x8 af[4], bfr[4];
#pragma unroll
      for (int i = 0; i < 4; ++i) {
        af[i] = *(const bf16x8*)(smA + ks * 4096 + (wr * 64 + i * 16 + lc) * 32 + quad * 8);
        bfr[i] = *(const bf16x8*)(smB + ks * 4096 + (wc * 64 + i * 16 + lc) * 32 + quad * 8);
      }
#pragma unroll
      for (int i = 0; i < 4; ++i)
#pragma unroll
        for (int j = 0; j < 4; ++j)
          acc[i][j] = __builtin_amdgcn_mfma_f32_16x16x32_bf16(af[i], bfr[j], acc[i][j], 0, 0, 0);
    }
    __syncthreads();
  }
}

// ---------- fused dual GEMM: z=0 -> row-major bf16 C (+ optional fused q2);
//            z=1 -> per-batch-transposed f16 ----------
__global__ __launch_bounds__(256) void k_gemm_nt(const u16* __restrict__ A,
                                                 const u16* __restrict__ Btn,
                                                 const u16* __restrict__ Btt,
                                                 u16* __restrict__ Cn,
                                                 u16* __restrict__ CtT,
                                                 float* __restrict__ q2out) {
  __shared__ u16 sm[16384];
  const int m0 = blockIdx.x * 128, n0 = blockIdx.y * 128;
  const u16* Bt = (blockIdx.z == 0) ? Btn : Btt;
  f32x4 acc[4][4];
#pragma unroll
  for (int i = 0; i < 4; ++i)
#pragma unroll
    for (int j = 0; j < 4; ++j) acc[i][j] = (f32x4){0.f, 0.f, 0.f, 0.f};
  gemm_core_bk64(A + (size_t)m0 * 1024, Bt + (size_t)n0 * 1024, 1024, 1024, 1024, sm, acc);
  const int tid = threadIdx.x, wave = tid >> 6;
  const int wr = wave >> 1, wc = wave & 1;
  const int lc = tid & 15, quad = (tid & 63) >> 4;
  if (blockIdx.z == 0) {
    float sq[4][4];
#pragma unroll
    for (int i = 0; i < 4; ++i)
#pragma unroll
      for (int r = 0; r < 4; ++r) sq[i][r] = 0.f;
#pragma unroll
    for (int i = 0; i < 4; ++i)
#pragma unroll
      for (int j = 0; j < 4; ++j) {
        const int n = n0 + wc * 64 + j * 16 + lc;
#pragma unroll
        for (int r = 0; r < 4; ++r) {
          const int m = m0 + wr * 64 + i * 16 + quad * 4 + r;
          const u16 v = f2b(acc[i][j][r]);
          Cn[(size_t)m * 1024 + n] = v;
          const float cv = __uint_as_float((u32)v << 16);
          sq[i][r] += cv * cv;
        }
      }
    if (q2out) {
      // reduce over lc (16 lanes within quad) -> per-head sum of squares
      const int h = (n0 >> 6) + wc;  // head index 0..15
#pragma unroll
      for (int i = 0; i < 4; ++i)
#pragma unroll
        for (int r = 0; r < 4; ++r) {
          float s = sq[i][r];
          s += __shfl_xor(s, 1);
          s += __shfl_xor(s, 2);
          s += __shfl_xor(s, 4);
          s += __shfl_xor(s, 8);
          if (lc == 0) {
            const int m = m0 + wr * 64 + i * 16 + quad * 4 + r;
            const int b = m >> 10, nrow = m & 1023;
            q2out[((size_t)(b * 16 + h)) * 1024 + nrow] = s;
          }
        }
    }
  } else {
    const int b = m0 >> 10, mloc = m0 & 1023;
    for (int half = 0; half < 2; ++half) {
      if (wc == half) {
#pragma unroll
        for (int i = 0; i < 4; ++i)
#pragma unroll
          for (int j = 0; j < 4; ++j)
#pragma unroll
            for (int r = 0; r < 4; ++r)
              sm[(j * 16 + lc) * 136 + wr * 64 + i * 16 + quad * 4 + r] = f2h(acc[i][j][r]);
      }
      __syncthreads();
#pragma unroll
      for (int it = 0; it < 4; ++it) {
        const int rr = it * 16 + (tid >> 4);
        const int c8 = (tid & 15) << 3;
        *(uint4*)&CtT[((size_t)(b * 1024 + n0 + half * 64 + rr)) * 1024 + mloc + c8] =
            *(const uint4*)&sm[rr * 136 + c8];
      }
      __syncthreads();
    }
  }
}

// ---------- GEMM + residual epilogue: out = res + acc*gamma[n] (fp32) ----------
__global__ __launch_bounds__(256) void k_gemm_res(const u16* __restrict__ A,
                                                  const u16* __restrict__ Bt,
                                                  const float* __restrict__ res,
                                                  const float* __restrict__ gamma,
                                                  float* __restrict__ out) {
  __shared__ u16 sm[16384];
  const int m0 = blockIdx.x * 128, n0 = blockIdx.y * 128;
  f32x4 acc[4][4];
#pragma unroll
  for (int i = 0; i < 4; ++i)
#pragma unroll
    for (int j = 0; j < 4; ++j) acc[i][j] = (f32x4){0.f, 0.f, 0.f, 0.f};
  gemm_core_bk64(A + (size_t)m0 * 1024, Bt + (size_t)n0 * 1024, 1024, 1024, 1024, sm, acc);
  const int tid = threadIdx.x, wave = tid >> 6;
  const int wr = wave >> 1, wc = wave & 1;
  const int lc = tid & 15, quad = (tid & 63) >> 4;
#pragma unroll
  for (int i = 0; i < 4; ++i)
#pragma unroll
    for (int j = 0; j < 4; ++j) {
      const int n = n0 + wc * 64 + j * 16 + lc;
      const float g = gamma[n];
#pragma unroll
      for (int r = 0; r < 4; ++r) {
        const size_t idx = (size_t)(m0 + wr * 64 + i * 16 + quad * 4 + r) * 1024 + n;
        out[idx] = res[idx] + acc[i][j][r] * g;
      }
    }
}

// ---------- token attention: 128-row q-tile, S^T trick, f16 P*V, XCD-local grid ----------
// (verified round-4 config: 256 threads, VGPR 84, 51.7KB LDS, ~73.6us)
__global__ __launch_bounds__(256, 3) void k_attn(const u16* __restrict__ qk,   // bf16
                                                 const u16* __restrict__ vT,   // f16 (B,D,N)
                                                 const float* __restrict__ q2,
                                                 const float* __restrict__ tau,
                                                 u16* __restrict__ outp) {
  const int bh = blockIdx.x & 127;
  const int q0 = (blockIdx.x >> 7) * 128;
  const int b = bh >> 4, h = bh & 15;
  __shared__ u16 sQ[8192];       // [128 q][64 d] bf16, swizzled chunks (16 KB)
  __shared__ u16 sK[4096];       // [64 k][64 d] bf16, swizzled chunks (8 KB)
  __shared__ u16 sV[4096];       // [64 d][64 n] f16,  swizzled chunks (8 KB)
  __shared__ u16 sP[128 * 72];   // [q][k] f16, padded (18 KB)
  __shared__ float sInv[128];
  const int tid = threadIdx.x;
  const int wave = tid >> 6;
  const int lane = tid & 63;
  const int lc = lane & 15, quad = lane >> 4;
  const int sw = lc & 7;         // xor swizzle key for fragment reads
  const float scale = tau[h] * 0.125f;  // 1/sqrt(64)
  const float two_scale = 2.0f * scale;
  const u16* qkb = qk + (size_t)b * (1024 * 1024) + h * 64;
  const u16* vTb = vT + ((size_t)b * 1024 + h * 64) * 1024;
  const float* q2g = q2 + (size_t)bh * 1024;

  const int r0 = tid >> 3, c0s = (tid & 7) ^ (r0 & 7);
  const int r1 = r0 + 32, c1s = (tid & 7) ^ (r1 & 7);

#pragma unroll
  for (int i = 0; i < 4; ++i)
    gl2lds16(qkb + (size_t)(q0 + i * 32 + r0) * 1024 + c0s * 8, sQ + i * 2048 + tid * 8);

  const int qr0 = wave * 32 + lc;
  const int qr1 = wave * 32 + 16 + lc;
  const float tq0 = q2g[q0 + qr0] * scale;
  const float tq1 = q2g[q0 + qr1] * scale;

  f32x4 oacc[2][4];
#pragma unroll
  for (int g = 0; g < 2; ++g)
#pragma unroll
    for (int j = 0; j < 4; ++j) oacc[g][j] = (f32x4){0.f, 0.f, 0.f, 0.f};
  float rsum[2] = {0.f, 0.f};

  for (int kt = 0; kt < 16; ++kt) {
    __syncthreads();
    const int kbase = kt * 64;
    gl2lds16(qkb + (size_t)(kbase + r0) * 1024 + c0s * 8, sK + tid * 8);
    gl2lds16(qkb + (size_t)(kbase + r1) * 1024 + c1s * 8, sK + 2048 + tid * 8);
    gl2lds16(vTb + (size_t)r0 * 1024 + kbase + c0s * 8, sV + tid * 8);
    gl2lds16(vTb + (size_t)r1 * 1024 + kbase + c1s * 8, sV + 2048 + tid * 8);
    __syncthreads();

    const bf16x8 aq00 = *(const bf16x8*)(sQ + (qr0 * 8 + (quad ^ sw)) * 8);
    const bf16x8 aq01 = *(const bf16x8*)(sQ + (qr0 * 8 + ((4 + quad) ^ sw)) * 8);
    const bf16x8 aq10 = *(const bf16x8*)(sQ + (qr1 * 8 + (quad ^ sw)) * 8);
    const bf16x8 aq11 = *(const bf16x8*)(sQ + (qr1 * 8 + ((4 + quad) ^ sw)) * 8);

    f32x4 s0[4], s1[4];
#pragma unroll
    for (int nb = 0; nb < 4; ++nb) {
      const int krow = nb * 16 + lc;
      const bf16x8 bk0 = *(const bf16x8*)(sK + (krow * 8 + (quad ^ sw)) * 8);
      const bf16x8 bk1 = *(const bf16x8*)(sK + (krow * 8 + ((4 + quad) ^ sw)) * 8);
      f32x4 z0 = (f32x4){0.f, 0.f, 0.f, 0.f};
      z0 = __builtin_amdgcn_mfma_f32_16x16x32_bf16(bk0, aq00, z0, 0, 0, 0);
      s0[nb] = __builtin_amdgcn_mfma_f32_16x16x32_bf16(bk1, aq01, z0, 0, 0, 0);
      f32x4 z1 = (f32x4){0.f, 0.f, 0.f, 0.f};
      z1 = __builtin_amdgcn_mfma_f32_16x16x32_bf16(bk0, aq10, z1, 0, 0, 0);
      s1[nb] = __builtin_amdgcn_mfma_f32_16x16x32_bf16(bk1, aq11, z1, 0, 0, 0);
    }
#pragma unroll
    for (int nb = 0; nb < 4; ++nb) {
      const float4 tk4 = *(const float4*)(q2g + kbase + nb * 16 + quad * 4);
      {
        const float e0 = __expf(fmaf(s0[nb][0], two_scale, -fmaf(tk4.x, scale, tq0)));
        const float e1 = __expf(fmaf(s0[nb][1], two_scale, -fmaf(tk4.y, scale, tq0)));
        const float e2 = __expf(fmaf(s0[nb][2], two_scale, -fmaf(tk4.z, scale, tq0)));
        const float e3 = __expf(fmaf(s0[nb][3], two_scale, -fmaf(tk4.w, scale, tq0)));
        *(uint2*)&sP[qr0 * 72 + nb * 16 + quad * 4] = make_uint2(pk2h(e0, e1), pk2h(e2, e3));
        rsum[0] += (e0 + e1) + (e2 + e3);
      }
      {
        const float e0 = __expf(fmaf(s1[nb][0], two_scale, -fmaf(tk4.x, scale, tq1)));
        const float e1 = __expf(fmaf(s1[nb][1], two_scale, -fmaf(tk4.y, scale, tq1)));
        const float e2 = __expf(fmaf(s1[nb][2], two_scale, -fmaf(tk4.z, scale, tq1)));
        const float e3 = __expf(fmaf(s1[nb][3], two_scale, -fmaf(tk4.w, scale, tq1)));
        *(uint2*)&sP[qr1 * 72 + nb * 16 + quad * 4] = make_uint2(pk2h(e0, e1), pk2h(e2, e3));
        rsum[1] += (e0 + e1) + (e2 + e3);
      }
    }
    const f16x8 ap00 = *(const f16x8*)&sP[qr0 * 72 + quad * 8];
    const f16x8 ap01 = *(const f16x8*)&sP[qr0 * 72 + 32 + quad * 8];
    const f16x8 ap10 = *(const f16x8*)&sP[qr1 * 72 + quad * 8];
    const f16x8 ap11 = *(const f16x8*)&sP[qr1 * 72 + 32 + quad * 8];
#pragma unroll
    for (int j2 = 0; j2 < 4; ++j2) {
      const int drow = j2 * 16 + lc;
      const f16x8 bv0 = *(const f16x8*)(sV + (drow * 8 + (quad ^ sw)) * 8);
      const f16x8 bv1 = *(const f16x8*)(sV + (drow * 8 + ((4 + quad) ^ sw)) * 8);
      oacc[0][j2] = __builtin_amdgcn_mfma_f32_16x16x32_f16(ap00, bv0, oacc[0][j2], 0, 0, 0);
      oacc[0][j2] = __builtin_amdgcn_mfma_f32_16x16x32_f16(ap01, bv1, oacc[0][j2], 0, 0, 0);
      oacc[1][j2] = __builtin_amdgcn_mfma_f32_16x16x32_f16(ap10, bv0, oacc[1][j2], 0, 0, 0);
      oacc[1][j2] = __builtin_amdgcn_mfma_f32_16x16x32_f16(ap11, bv1, oacc[1][j2], 0, 0, 0);
    }
  }
#pragma unroll
  for (int g = 0; g < 2; ++g) {
    float rs = rsum[g];
    rs += __shfl_xor(rs, 16);
    rs += __shfl_xor(rs, 32);
    if (lane < 16) sInv[wave * 32 + g * 16 + lane] = 1.f / rs;
  }
#pragma unroll
  for (int g = 0; g < 2; ++g)
#pragma unroll
    for (int r = 0; r < 4; ++r) {
      const int row = wave * 32 + g * 16 + quad * 4 + r;
      const float inv = sInv[row];
      u16* o = outp + ((size_t)(b * 1024 + q0 + row)) * 1024 + h * 64;
#pragma unroll
      for (int j2 = 0; j2 < 4; ++j2) o[j2 * 16 + lc] = f2b(oacc[g][j2][r] * inv);
    }
}

// ---------- channel attention matrix: softmax(scaled X^T X); diag(Gram) = q2 fused ----------
__global__ __launch_bounds__(256) void k_chan_s(const u16* __restrict__ qkcT,  // f16
                                                const float* __restrict__ tau,
                                                u16* __restrict__ Aout) {      // bf16
  const int bc = blockIdx.x, b = bc >> 3, c = bc & 7;
  __shared__ u16 sX[8192];
  __shared__ float sq2[128];
  const int tid = threadIdx.x, wave = tid >> 6, lane = tid & 63;
  const int lc = lane & 15, quad = lane >> 4;
  const u16* Xb = qkcT + ((size_t)b * 1024 + c * 128) * 1024;
  f32x4 acc[2][8];
#pragma unroll
  for (int i = 0; i < 2; ++i)
#pragma unroll
    for (int j = 0; j < 8; ++j) acc[i][j] = (f32x4){0.f, 0.f, 0.f, 0.f};
  for (int nt = 0; nt < 1024; nt += 64) {
#pragma unroll
    for (int i = 0; i < 4; ++i) {
      const int idx = i * 256 + tid;
      gl2lds16(Xb + (size_t)(idx >> 3) * 1024 + nt + ((idx & 7) << 3), sX + idx * 8);
    }
    __syncthreads();
    f16x8 af[2][2];
#pragma unroll
    for (int i = 0; i < 2; ++i)
#pragma unroll
      for (int ks = 0; ks < 2; ++ks)
        af[i][ks] =
            *(const f16x8*)&sX[((wave * 2 + i) * 16 + lc) * 64 + ks * 32 + quad * 8];
#pragma unroll
    for (int nb = 0; nb < 8; ++nb)
#pragma unroll
      for (int ks = 0; ks < 2; ++ks) {
        const f16x8 bb = *(const f16x8*)&sX[(nb * 16 + lc) * 64 + ks * 32 + quad * 8];
        acc[0][nb] = __builtin_amdgcn_mfma_f32_16x16x32_f16(af[0][ks], bb, acc[0][nb], 0, 0, 0);
        acc[1][nb] = __builtin_amdgcn_mfma_f32_16x16x32_f16(af[1][ks], bb, acc[1][nb], 0, 0, 0);
      }
    __syncthreads();
  }
#pragma unroll
  for (int i = 0; i < 2; ++i) {
    const int nbd = wave * 2 + i;
    if ((lc >> 2) == quad) sq2[nbd * 16 + lc] = acc[i][nbd][lc & 3];
  }
  __syncthreads();
  const float scl = tau[c] * (1.f / 32.f);  // 1/sqrt(1024)
#pragma unroll
  for (int i = 0; i < 2; ++i) {
    const int rbase = (wave * 2 + i) * 16 + quad * 4;
#pragma unroll
    for (int r = 0; r < 4; ++r) {
      const float q2r = sq2[rbase + r];
      float ee[8];
      float ps = 0.f;
#pragma unroll
      for (int nb = 0; nb < 8; ++nb) {
        const float e = __expf((2.f * acc[i][nb][r] - q2r - sq2[nb * 16 + lc]) * scl);
        ee[nb] = e;
        ps += e;
      }
      ps += __shfl_xor(ps, 1);
      ps += __shfl_xor(ps, 2);
      ps += __shfl_xor(ps, 4);
      ps += __shfl_xor(ps, 8);
      const float inv = 1.f / ps;
      u16* Ao = Aout + (size_t)bc * 16384 + (size_t)(rbase + r) * 128;
#pragma unroll
      for (int nb = 0; nb < 8; ++nb) Ao[nb * 16 + lc] = f2b(ee[nb] * inv);
    }
  }
}

// ---------- channel PV: out[b,n,c*128+d] = sum_d' vc[b,n,c*128+d'] * A[d][d'] ----------
__global__ __launch_bounds__(256) void k_chan_pv(const u16* __restrict__ vc,
                                                 const u16* __restrict__ Ac,
                                                 u16* __restrict__ outp) {
  __shared__ u16 sm[16384];
  const int bc = blockIdx.y, b = bc >> 3, c = bc & 7;
  const int m0 = blockIdx.x * 128;
  f32x4 acc[4][4];
#pragma unroll
  for (int i = 0; i < 4; ++i)
#pragma unroll
    for (int j = 0; j < 4; ++j) acc[i][j] = (f32x4){0.f, 0.f, 0.f, 0.f};
  gemm_core_bk64(vc + ((size_t)b * 1024 + m0) * 1024 + c * 128, Ac + (size_t)bc * 16384,
                 1024, 128, 128, sm, acc);
  const int tid = threadIdx.x, wave = tid >> 6;
  const int wr = wave >> 1, wc = wave & 1;
  const int lc = tid & 15, quad = (tid & 63) >> 4;
#pragma unroll
  for (int i = 0; i < 4; ++i)
#pragma unroll
    for (int j = 0; j < 4; ++j)
#pragma unroll
      for (int r = 0; r < 4; ++r)
        outp[((size_t)(b * 1024 + m0 + wr * 64 + i * 16 + quad * 4 + r)) * 1024 + c * 128 +
             wc * 64 + j * 16 + lc] = f2b(acc[i][j][r]);
}

extern "C" void kernel_launch(void* const* d_in, const int* in_sizes, int n_in,
                              void* d_out, int out_size, void* d_ws, size_t ws_size,
                              hipStream_t stream) {
  (void)in_sizes; (void)n_in; (void)out_size; (void)ws_size;
  const float* x = (const float*)d_in[0];
  const float* tau_t = (const float*)d_in[4];
  const float* tau_c = (const float*)d_in[8];
  const float* ln1w = (const float*)d_in[9];
  const float* ln1b = (const float*)d_in[10];
  const float* ln2w = (const float*)d_in[11];
  const float* ln2b = (const float*)d_in[12];
  const float* g1 = (const float*)d_in[13];
  const float* g2 = (const float*)d_in[14];
  float* out = (float*)d_out;

  // workspace carve-up
  char* p = (char*)d_ws;
  u16* wb[6];
  for (int i = 0; i < 6; ++i) wb[i] = (u16*)(p + (size_t)i * (2u << 20));
  u16* bufA = (u16*)(p + (size_t)12 * (1u << 20));       // 16 MB
  u16* bufQ = bufA + (size_t)8 * 1024 * 1024;            // 16 MB
  u16* bufV = bufQ + (size_t)8 * 1024 * 1024;            // 16 MB
  float* q2b = (float*)(bufV + (size_t)8 * 1024 * 1024); // 512 KB
  u16* Ac = (u16*)(q2b + 131072 + 8192);                 // 2 MB

  W6 w6;
  const int widx[6] = {1, 2, 3, 5, 6, 7};  // Wqk_t, Wv_t, Wo_t, Wqk_c, Wv_c, Wo_c
  for (int i = 0; i < 6; ++i) { w6.src[i] = (const float*)d_in[widx[i]]; w6.dst[i] = wb[i]; }
  k_wtrans6<<<dim3(16, 16, 6), 256, 0, stream>>>(w6);

  // ---- token diffusion ----
  k_ln<<<8192, 256, 0, stream>>>(x, ln1w, ln1b, bufA);                           // y1 (bf16)
  k_gemm_nt<<<dim3(64, 8, 2), 256, 0, stream>>>(bufA, wb[0], wb[1], bufQ, bufV, q2b);  // qk+q2, v^T
  k_attn<<<1024, 256, 0, stream>>>(bufQ, bufV, q2b, tau_t, bufA);                // attn_out bf16
  k_gemm_res<<<dim3(64, 8), 256, 0, stream>>>(bufA, wb[2], x, g1, out);          // x1 = x + Wo*g1

  // ---- channel diffusion ----
  k_ln<<<8192, 256, 0, stream>>>(out, ln2w, ln2b, bufQ);                         // y2 (bf16)
  k_gemm_nt<<<dim3(64, 8, 2), 256, 0, stream>>>(bufQ, wb[4], wb[3], bufA, bufV, nullptr); // vc, qkc^T
  k_chan_s<<<64, 256, 0, stream>>>(bufV, tau_c, Ac);                             // softmax matrix
  k_chan_pv<<<dim3(8, 64), 256, 0, stream>>>(bufA, Ac, bufQ);                    // chan attn out bf16
  k_gemm_res<<<dim3(64, 8), 256, 0, stream>>>(bufQ, wb[5], out, g2, out);        // out = x1 + Wo*g2
}

// Round 7
// 389.973 us; speedup vs baseline: 1.1152x; 1.0297x over previous
//
#include <hip/hip_runtime.h>

typedef unsigned short u16;
typedef unsigned int u32;
typedef __bf16 bf16x8 __attribute__((ext_vector_type(8)));
typedef _Float16 f16x8 __attribute__((ext_vector_type(8)));
typedef __fp16 fp16x2 __attribute__((ext_vector_type(2)));
typedef float f32x4 __attribute__((ext_vector_type(4)));

__device__ __forceinline__ u16 f2b(float f) {
  u32 u = __float_as_uint(f);
  return (u16)((u + 0x7FFFu + ((u >> 16) & 1u)) >> 16);
}
__device__ __forceinline__ u16 f2h(float f) {
  union { _Float16 h; u16 u; } c;
  c.h = (_Float16)f;
  return c.u;
}
__device__ __forceinline__ u32 pk2h(float a, float b) {
  union { fp16x2 v; u32 u; } c;
  c.v = __builtin_amdgcn_cvt_pkrtz(a, b);
  return c.u;
}
__device__ __forceinline__ float sumsq2(u32 u) {  // bf16 pair
  float lo = __uint_as_float(u << 16);
  float hi = __uint_as_float(u & 0xFFFF0000u);
  return lo * lo + hi * hi;
}
__device__ __forceinline__ void gl2lds16(const void* g, void* l) {
  __builtin_amdgcn_global_load_lds((__attribute__((address_space(1))) void*)g,
                                   (__attribute__((address_space(3))) void*)l, 16, 0, 0);
}

// ---------- fused fp32 -> bf16 transposed weights (all 6 in one launch) ----------
struct W6 {
  const float* src[6];
  u16* dst[6];
};
__global__ __launch_bounds__(256) void k_wtrans6(W6 p) {
  const float* __restrict__ W = p.src[blockIdx.z];
  u16* __restrict__ Wt = p.dst[blockIdx.z];
  __shared__ float sm[64 * 65];
  const int r0 = blockIdx.y * 64, c0 = blockIdx.x * 64;
  const int tid = threadIdx.x;
#pragma unroll
  for (int i = 0; i < 16; ++i) {
    int idx = i * 256 + tid;
    int r = idx >> 6, c = idx & 63;
    sm[c * 65 + r] = W[(size_t)(r0 + r) * 1024 + c0 + c];
  }
  __syncthreads();
#pragma unroll
  for (int i = 0; i < 16; ++i) {
    int idx = i * 256 + tid;
    int r = idx >> 6, c = idx & 63;
    Wt[(size_t)(c0 + r) * 1024 + r0 + c] = f2b(sm[r * 65 + c]);
  }
}

// ---------- layernorm fp32 -> bf16 ----------
__global__ __launch_bounds__(256) void k_ln(const float* __restrict__ x,
                                            const float* __restrict__ w,
                                            const float* __restrict__ bb,
                                            u16* __restrict__ y) {
  const int row = blockIdx.x;
  const int tid = threadIdx.x;
  const float4 v = ((const float4*)(x + (size_t)row * 1024))[tid];
  float s = v.x + v.y + v.z + v.w;
  float s2 = v.x * v.x + v.y * v.y + v.z * v.z + v.w * v.w;
  for (int o = 32; o > 0; o >>= 1) {
    s += __shfl_down(s, o);
    s2 += __shfl_down(s2, o);
  }
  __shared__ float red[8];
  const int wave = tid >> 6;
  if ((tid & 63) == 0) { red[wave * 2] = s; red[wave * 2 + 1] = s2; }
  __syncthreads();
  s = red[0] + red[2] + red[4] + red[6];
  s2 = red[1] + red[3] + red[5] + red[7];
  const float mu = s * (1.0f / 1024.0f);
  const float var = s2 * (1.0f / 1024.0f) - mu * mu;
  const float rs = rsqrtf(var + 1e-5f);
  const float4 wv = ((const float4*)w)[tid];
  const float4 bv = ((const float4*)bb)[tid];
  u16* yr = y + (size_t)row * 1024 + tid * 4;
  yr[0] = f2b((v.x - mu) * rs * wv.x + bv.x);
  yr[1] = f2b((v.y - mu) * rs * wv.y + bv.y);
  yr[2] = f2b((v.z - mu) * rs * wv.z + bv.z);
  yr[3] = f2b((v.w - mu) * rs * wv.w + bv.w);
}

// ---------- 128x128-tile bf16 MFMA GEMM core, BK=64 (two 32-k sub-tiles/barrier) ----------
__device__ __forceinline__ void gemm_core_bk64(const u16* __restrict__ Ab,
                                               const u16* __restrict__ Bb,
                                               int lda, int ldb, int K,
                                               u16* sm, f32x4 acc[4][4]) {
  const int tid = threadIdx.x;
  const int wave = tid >> 6;
  const int wr = wave >> 1, wc = wave & 1;
  const int lane = tid & 63;
  const int lc = lane & 15, quad = lane >> 4;
  u16* smA = sm;
  u16* smB = sm + 8192;
  const int sr = tid >> 2, sk = (tid & 3) << 3;
  const u16* gA = Ab + (size_t)sr * lda + sk;
  const u16* gB = Bb + (size_t)sr * ldb + sk;
  const size_t a64 = (size_t)64 * lda, b64 = (size_t)64 * ldb;
  u16* dA = smA + tid * 8;
  u16* dB = smB + tid * 8;
  for (int kt = 0; kt < K; kt += 64) {
    gl2lds16(gA + kt, dA);
    gl2lds16(gA + a64 + kt, dA + 2048);
    gl2lds16(gB + kt, dB);
    gl2lds16(gB + b64 + kt, dB + 2048);
    gl2lds16(gA + kt + 32, dA + 4096);
    gl2lds16(gA + a64 + kt + 32, dA + 6144);
    gl2lds16(gB + kt + 32, dB + 4096);
    gl2lds16(gB + b64 + kt + 32, dB + 6144);
    __syncthreads();
#pragma unroll
    for (int ks = 0; ks < 2; ++ks) {
      bf16x8 af[4], bfr[4];
#pragma unroll
      for (int i = 0; i < 4; ++i) {
        af[i] = *(const bf16x8*)(smA + ks * 4096 + (wr * 64 + i * 16 + lc) * 32 + quad * 8);
        bfr[i] = *(const bf16x8*)(smB + ks * 4096 + (wc * 64 + i * 16 + lc) * 32 + quad * 8);
      }
#pragma unroll
      for (int i = 0; i < 4; ++i)
#pragma unroll
        for (int j = 0; j < 4; ++j)
          acc[i][j] = __builtin_amdgcn_mfma_f32_16x16x32_bf16(af[i], bfr[j], acc[i][j], 0, 0, 0);
    }
    __syncthreads();
  }
}

// ---------- fused dual GEMM: z=0 -> row-major bf16 C (+ optional fused q2);
//            z=1 -> per-batch-transposed f16 ----------
__global__ __launch_bounds__(256) void k_gemm_nt(const u16* __restrict__ A,
                                                 const u16* __restrict__ Btn,
                                                 const u16* __restrict__ Btt,
                                                 u16* __restrict__ Cn,
                                                 u16* __restrict__ CtT,
                                                 float* __restrict__ q2out) {
  __shared__ u16 sm[16384];
  const int m0 = blockIdx.x * 128, n0 = blockIdx.y * 128;
  const u16* Bt = (blockIdx.z == 0) ? Btn : Btt;
  f32x4 acc[4][4];
#pragma unroll
  for (int i = 0; i < 4; ++i)
#pragma unroll
    for (int j = 0; j < 4; ++j) acc[i][j] = (f32x4){0.f, 0.f, 0.f, 0.f};
  gemm_core_bk64(A + (size_t)m0 * 1024, Bt + (size_t)n0 * 1024, 1024, 1024, 1024, sm, acc);
  const int tid = threadIdx.x, wave = tid >> 6;
  const int wr = wave >> 1, wc = wave & 1;
  const int lc = tid & 15, quad = (tid & 63) >> 4;
  if (blockIdx.z == 0) {
    float sq[4][4];
#pragma unroll
    for (int i = 0; i < 4; ++i)
#pragma unroll
      for (int r = 0; r < 4; ++r) sq[i][r] = 0.f;
#pragma unroll
    for (int i = 0; i < 4; ++i)
#pragma unroll
      for (int j = 0; j < 4; ++j) {
        const int n = n0 + wc * 64 + j * 16 + lc;
#pragma unroll
        for (int r = 0; r < 4; ++r) {
          const int m = m0 + wr * 64 + i * 16 + quad * 4 + r;
          const u16 v = f2b(acc[i][j][r]);
          Cn[(size_t)m * 1024 + n] = v;
          const float cv = __uint_as_float((u32)v << 16);
          sq[i][r] += cv * cv;
        }
      }
    if (q2out) {
      const int h = (n0 >> 6) + wc;  // head index 0..15
#pragma unroll
      for (int i = 0; i < 4; ++i)
#pragma unroll
        for (int r = 0; r < 4; ++r) {
          float s = sq[i][r];
          s += __shfl_xor(s, 1);
          s += __shfl_xor(s, 2);
          s += __shfl_xor(s, 4);
          s += __shfl_xor(s, 8);
          if (lc == 0) {
            const int m = m0 + wr * 64 + i * 16 + quad * 4 + r;
            const int b = m >> 10, nrow = m & 1023;
            q2out[((size_t)(b * 16 + h)) * 1024 + nrow] = s;
          }
        }
    }
  } else {
    const int b = m0 >> 10, mloc = m0 & 1023;
    for (int half = 0; half < 2; ++half) {
      if (wc == half) {
#pragma unroll
        for (int i = 0; i < 4; ++i)
#pragma unroll
          for (int j = 0; j < 4; ++j)
#pragma unroll
            for (int r = 0; r < 4; ++r)
              sm[(j * 16 + lc) * 136 + wr * 64 + i * 16 + quad * 4 + r] = f2h(acc[i][j][r]);
      }
      __syncthreads();
#pragma unroll
      for (int it = 0; it < 4; ++it) {
        const int rr = it * 16 + (tid >> 4);
        const int c8 = (tid & 15) << 3;
        *(uint4*)&CtT[((size_t)(b * 1024 + n0 + half * 64 + rr)) * 1024 + mloc + c8] =
            *(const uint4*)&sm[rr * 136 + c8];
      }
      __syncthreads();
    }
  }
}

// ---------- GEMM + residual epilogue: out = res + acc*gamma[n] (fp32) ----------
__global__ __launch_bounds__(256) void k_gemm_res(const u16* __restrict__ A,
                                                  const u16* __restrict__ Bt,
                                                  const float* __restrict__ res,
                                                  const float* __restrict__ gamma,
                                                  float* __restrict__ out) {
  __shared__ u16 sm[16384];
  const int m0 = blockIdx.x * 128, n0 = blockIdx.y * 128;
  f32x4 acc[4][4];
#pragma unroll
  for (int i = 0; i < 4; ++i)
#pragma unroll
    for (int j = 0; j < 4; ++j) acc[i][j] = (f32x4){0.f, 0.f, 0.f, 0.f};
  gemm_core_bk64(A + (size_t)m0 * 1024, Bt + (size_t)n0 * 1024, 1024, 1024, 1024, sm, acc);
  const int tid = threadIdx.x, wave = tid >> 6;
  const int wr = wave >> 1, wc = wave & 1;
  const int lc = tid & 15, quad = (tid & 63) >> 4;
#pragma unroll
  for (int i = 0; i < 4; ++i)
#pragma unroll
    for (int j = 0; j < 4; ++j) {
      const int n = n0 + wc * 64 + j * 16 + lc;
      const float g = gamma[n];
#pragma unroll
      for (int r = 0; r < 4; ++r) {
        const size_t idx = (size_t)(m0 + wr * 64 + i * 16 + quad * 4 + r) * 1024 + n;
        out[idx] = res[idx] + acc[i][j][r] * g;
      }
    }
}

// ---------- token attention: 128-row q-tile, Q staged through sP, 34.5KB LDS ----------
// grid: 1024 1-D blocks, id = qt*128 + bh -> XCD = bh%8 (K/V L2 locality).
// LDS 34.5KB -> 4 blocks/CU; 1024 blocks = exactly one residency round (no tail).
__global__ __launch_bounds__(256, 4) void k_attn(const u16* __restrict__ qk,   // bf16
                                                 const u16* __restrict__ vT,   // f16 (B,D,N)
                                                 const float* __restrict__ q2,
                                                 const float* __restrict__ tau,
                                                 u16* __restrict__ outp) {
  const int bh = blockIdx.x & 127;
  const int q0 = (blockIdx.x >> 7) * 128;
  const int b = bh >> 4, h = bh & 15;
  __shared__ u16 sK[4096];      // [64 k][64 d] bf16, swizzled chunks (8 KB)
  __shared__ u16 sV[4096];      // [64 d][64 n] f16,  swizzled chunks (8 KB)
  __shared__ u16 sP[9216];      // P [128 q][72 k] f16 (18 KB); transiently holds Q tile
  __shared__ float sInv[128];
  const int tid = threadIdx.x;
  const int wave = tid >> 6;
  const int lane = tid & 63;
  const int lc = lane & 15, quad = lane >> 4;
  const int sw = lc & 7;         // xor swizzle key for fragment reads
  const float scale = tau[h] * 0.125f;  // 1/sqrt(64)
  const float two_scale = 2.0f * scale;
  const u16* qkb = qk + (size_t)b * (1024 * 1024) + h * 64;
  const u16* vTb = vT + ((size_t)b * 1024 + h * 64) * 1024;
  const float* q2g = q2 + (size_t)bh * 1024;

  const int r0 = tid >> 3, c0s = (tid & 7) ^ (r0 & 7);
  const int r1 = r0 + 32, c1s = (tid & 7) ^ (r1 & 7);

  // stage Q tile (128 rows x 64 d) into sP region (transient, flat [row*64] layout)
#pragma unroll
  for (int i = 0; i < 4; ++i)
    gl2lds16(qkb + (size_t)(q0 + i * 32 + r0) * 1024 + c0s * 8, sP + i * 2048 + tid * 8);
  __syncthreads();  // Q landed

  const int qr0 = wave * 32 + lc;
  const int qr1 = wave * 32 + 16 + lc;
  // Q fragments -> registers (loop-invariant); sP reused for P after first loop barrier
  const bf16x8 aq00 = *(const bf16x8*)(sP + (qr0 * 8 + (quad ^ sw)) * 8);
  const bf16x8 aq01 = *(const bf16x8*)(sP + (qr0 * 8 + ((4 + quad) ^ sw)) * 8);
  const bf16x8 aq10 = *(const bf16x8*)(sP + (qr1 * 8 + (quad ^ sw)) * 8);
  const bf16x8 aq11 = *(const bf16x8*)(sP + (qr1 * 8 + ((4 + quad) ^ sw)) * 8);
  const float tq0 = q2g[q0 + qr0] * scale;
  const float tq1 = q2g[q0 + qr1] * scale;

  f32x4 oacc[2][4];
#pragma unroll
  for (int g = 0; g < 2; ++g)
#pragma unroll
    for (int j = 0; j < 4; ++j) oacc[g][j] = (f32x4){0.f, 0.f, 0.f, 0.f};
  float rsum[2] = {0.f, 0.f};

  for (int kt = 0; kt < 16; ++kt) {
    __syncthreads();  // (A) all waves done with prev sK/sV reads AND (kt=0) Q-frag reads
    const int kbase = kt * 64;
    gl2lds16(qkb + (size_t)(kbase + r0) * 1024 + c0s * 8, sK + tid * 8);
    gl2lds16(qkb + (size_t)(kbase + r1) * 1024 + c1s * 8, sK + 2048 + tid * 8);
    gl2lds16(vTb + (size_t)r0 * 1024 + kbase + c0s * 8, sV + tid * 8);
    gl2lds16(vTb + (size_t)r1 * 1024 + kbase + c1s * 8, sV + 2048 + tid * 8);
    __syncthreads();  // (B) K/V landed

    f32x4 s0[4], s1[4];
#pragma unroll
    for (int nb = 0; nb < 4; ++nb) {
      const int krow = nb * 16 + lc;
      const bf16x8 bk0 = *(const bf16x8*)(sK + (krow * 8 + (quad ^ sw)) * 8);
      const bf16x8 bk1 = *(const bf16x8*)(sK + (krow * 8 + ((4 + quad) ^ sw)) * 8);
      f32x4 z0 = (f32x4){0.f, 0.f, 0.f, 0.f};
      z0 = __builtin_amdgcn_mfma_f32_16x16x32_bf16(bk0, aq00, z0, 0, 0, 0);
      s0[nb] = __builtin_amdgcn_mfma_f32_16x16x32_bf16(bk1, aq01, z0, 0, 0, 0);
      f32x4 z1 = (f32x4){0.f, 0.f, 0.f, 0.f};
      z1 = __builtin_amdgcn_mfma_f32_16x16x32_bf16(bk0, aq10, z1, 0, 0, 0);
      s1[nb] = __builtin_amdgcn_mfma_f32_16x16x32_bf16(bk1, aq11, z1, 0, 0, 0);
    }
#pragma unroll
    for (int nb = 0; nb < 4; ++nb) {
      const float4 tk4 = *(const float4*)(q2g + kbase + nb * 16 + quad * 4);
      {
        const float e0 = __expf(fmaf(s0[nb][0], two_scale, -fmaf(tk4.x, scale, tq0)));
        const float e1 = __expf(fmaf(s0[nb][1], two_scale, -fmaf(tk4.y, scale, tq0)));
        const float e2 = __expf(fmaf(s0[nb][2], two_scale, -fmaf(tk4.z, scale, tq0)));
        const float e3 = __expf(fmaf(s0[nb][3], two_scale, -fmaf(tk4.w, scale, tq0)));
        *(uint2*)&sP[qr0 * 72 + nb * 16 + quad * 4] = make_uint2(pk2h(e0, e1), pk2h(e2, e3));
        rsum[0] += (e0 + e1) + (e2 + e3);
      }
      {
        const float e0 = __expf(fmaf(s1[nb][0], two_scale, -fmaf(tk4.x, scale, tq1)));
        const float e1 = __expf(fmaf(s1[nb][1], two_scale, -fmaf(tk4.y, scale, tq1)));
        const float e2 = __expf(fmaf(s1[nb][2], two_scale, -fmaf(tk4.z, scale, tq1)));
        const float e3 = __expf(fmaf(s1[nb][3], two_scale, -fmaf(tk4.w, scale, tq1)));
        *(uint2*)&sP[qr1 * 72 + nb * 16 + quad * 4] = make_uint2(pk2h(e0, e1), pk2h(e2, e3));
        rsum[1] += (e0 + e1) + (e2 + e3);
      }
    }
    const f16x8 ap00 = *(const f16x8*)&sP[qr0 * 72 + quad * 8];
    const f16x8 ap01 = *(const f16x8*)&sP[qr0 * 72 + 32 + quad * 8];
    const f16x8 ap10 = *(const f16x8*)&sP[qr1 * 72 + quad * 8];
    const f16x8 ap11 = *(const f16x8*)&sP[qr1 * 72 + 32 + quad * 8];
#pragma unroll
    for (int j2 = 0; j2 < 4; ++j2) {
      const int drow = j2 * 16 + lc;
      const f16x8 bv0 = *(const f16x8*)(sV + (drow * 8 + (quad ^ sw)) * 8);
      const f16x8 bv1 = *(const f16x8*)(sV + (drow * 8 + ((4 + quad) ^ sw)) * 8);
      oacc[0][j2] = __builtin_amdgcn_mfma_f32_16x16x32_f16(ap00, bv0, oacc[0][j2], 0, 0, 0);
      oacc[0][j2] = __builtin_amdgcn_mfma_f32_16x16x32_f16(ap01, bv1, oacc[0][j2], 0, 0, 0);
      oacc[1][j2] = __builtin_amdgcn_mfma_f32_16x16x32_f16(ap10, bv0, oacc[1][j2], 0, 0, 0);
      oacc[1][j2] = __builtin_amdgcn_mfma_f32_16x16x32_f16(ap11, bv1, oacc[1][j2], 0, 0, 0);
    }
  }
#pragma unroll
  for (int g = 0; g < 2; ++g) {
    float rs = rsum[g];
    rs += __shfl_xor(rs, 16);
    rs += __shfl_xor(rs, 32);
    if (lane < 16) sInv[wave * 32 + g * 16 + lane] = 1.f / rs;
  }
#pragma unroll
  for (int g = 0; g < 2; ++g)
#pragma unroll
    for (int r = 0; r < 4; ++r) {
      const int row = wave * 32 + g * 16 + quad * 4 + r;
      const float inv = sInv[row];
      u16* o = outp + ((size_t)(b * 1024 + q0 + row)) * 1024 + h * 64;
#pragma unroll
      for (int j2 = 0; j2 < 4; ++j2) o[j2 * 16 + lc] = f2b(oacc[g][j2][r] * inv);
    }
}

// ---------- channel attention matrix: softmax(scaled X^T X); diag(Gram) = q2 fused ----------
__global__ __launch_bounds__(256) void k_chan_s(const u16* __restrict__ qkcT,  // f16
                                                const float* __restrict__ tau,
                                                u16* __restrict__ Aout) {      // bf16
  const int bc = blockIdx.x, b = bc >> 3, c = bc & 7;
  __shared__ u16 sX[8192];
  __shared__ float sq2[128];
  const int tid = threadIdx.x, wave = tid >> 6, lane = tid & 63;
  const int lc = lane & 15, quad = lane >> 4;
  const u16* Xb = qkcT + ((size_t)b * 1024 + c * 128) * 1024;
  f32x4 acc[2][8];
#pragma unroll
  for (int i = 0; i < 2; ++i)
#pragma unroll
    for (int j = 0; j < 8; ++j) acc[i][j] = (f32x4){0.f, 0.f, 0.f, 0.f};
  for (int nt = 0; nt < 1024; nt += 64) {
#pragma unroll
    for (int i = 0; i < 4; ++i) {
      const int idx = i * 256 + tid;
      gl2lds16(Xb + (size_t)(idx >> 3) * 1024 + nt + ((idx & 7) << 3), sX + idx * 8);
    }
    __syncthreads();
    f16x8 af[2][2];
#pragma unroll
    for (int i = 0; i < 2; ++i)
#pragma unroll
      for (int ks = 0; ks < 2; ++ks)
        af[i][ks] =
            *(const f16x8*)&sX[((wave * 2 + i) * 16 + lc) * 64 + ks * 32 + quad * 8];
#pragma unroll
    for (int nb = 0; nb < 8; ++nb)
#pragma unroll
      for (int ks = 0; ks < 2; ++ks) {
        const f16x8 bb = *(const f16x8*)&sX[(nb * 16 + lc) * 64 + ks * 32 + quad * 8];
        acc[0][nb] = __builtin_amdgcn_mfma_f32_16x16x32_f16(af[0][ks], bb, acc[0][nb], 0, 0, 0);
        acc[1][nb] = __builtin_amdgcn_mfma_f32_16x16x32_f16(af[1][ks], bb, acc[1][nb], 0, 0, 0);
      }
    __syncthreads();
  }
#pragma unroll
  for (int i = 0; i < 2; ++i) {
    const int nbd = wave * 2 + i;
    if ((lc >> 2) == quad) sq2[nbd * 16 + lc] = acc[i][nbd][lc & 3];
  }
  __syncthreads();
  const float scl = tau[c] * (1.f / 32.f);  // 1/sqrt(1024)
#pragma unroll
  for (int i = 0; i < 2; ++i) {
    const int rbase = (wave * 2 + i) * 16 + quad * 4;
#pragma unroll
    for (int r = 0; r < 4; ++r) {
      const float q2r = sq2[rbase + r];
      float ee[8];
      float ps = 0.f;
#pragma unroll
      for (int nb = 0; nb < 8; ++nb) {
        const float e = __expf((2.f * acc[i][nb][r] - q2r - sq2[nb * 16 + lc]) * scl);
        ee[nb] = e;
        ps += e;
      }
      ps += __shfl_xor(ps, 1);
      ps += __shfl_xor(ps, 2);
      ps += __shfl_xor(ps, 4);
      ps += __shfl_xor(ps, 8);
      const float inv = 1.f / ps;
      u16* Ao = Aout + (size_t)bc * 16384 + (size_t)(rbase + r) * 128;
#pragma unroll
      for (int nb = 0; nb < 8; ++nb) Ao[nb * 16 + lc] = f2b(ee[nb] * inv);
    }
  }
}

// ---------- channel PV: out[b,n,c*128+d] = sum_d' vc[b,n,c*128+d'] * A[d][d'] ----------
__global__ __launch_bounds__(256) void k_chan_pv(const u16* __restrict__ vc,
                                                 const u16* __restrict__ Ac,
                                                 u16* __restrict__ outp) {
  __shared__ u16 sm[16384];
  const int bc = blockIdx.y, b = bc >> 3, c = bc & 7;
  const int m0 = blockIdx.x * 128;
  f32x4 acc[4][4];
#pragma unroll
  for (int i = 0; i < 4; ++i)
#pragma unroll
    for (int j = 0; j < 4; ++j) acc[i][j] = (f32x4){0.f, 0.f, 0.f, 0.f};
  gemm_core_bk64(vc + ((size_t)b * 1024 + m0) * 1024 + c * 128, Ac + (size_t)bc * 16384,
                 1024, 128, 128, sm, acc);
  const int tid = threadIdx.x, wave = tid >> 6;
  const int wr = wave >> 1, wc = wave & 1;
  const int lc = tid & 15, quad = (tid & 63) >> 4;
#pragma unroll
  for (int i = 0; i < 4; ++i)
#pragma unroll
    for (int j = 0; j < 4; ++j)
#pragma unroll
      for (int r = 0; r < 4; ++r)
        outp[((size_t)(b * 1024 + m0 + wr * 64 + i * 16 + quad * 4 + r)) * 1024 + c * 128 +
             wc * 64 + j * 16 + lc] = f2b(acc[i][j][r]);
}

extern "C" void kernel_launch(void* const* d_in, const int* in_sizes, int n_in,
                              void* d_out, int out_size, void* d_ws, size_t ws_size,
                              hipStream_t stream) {
  (void)in_sizes; (void)n_in; (void)out_size; (void)ws_size;
  const float* x = (const float*)d_in[0];
  const float* tau_t = (const float*)d_in[4];
  const float* tau_c = (const float*)d_in[8];
  const float* ln1w = (const float*)d_in[9];
  const float* ln1b = (const float*)d_in[10];
  const float* ln2w = (const float*)d_in[11];
  const float* ln2b = (const float*)d_in[12];
  const float* g1 = (const float*)d_in[13];
  const float* g2 = (const float*)d_in[14];
  float* out = (float*)d_out;

  // workspace carve-up
  char* p = (char*)d_ws;
  u16* wb[6];
  for (int i = 0; i < 6; ++i) wb[i] = (u16*)(p + (size_t)i * (2u << 20));
  u16* bufA = (u16*)(p + (size_t)12 * (1u << 20));       // 16 MB
  u16* bufQ = bufA + (size_t)8 * 1024 * 1024;            // 16 MB
  u16* bufV = bufQ + (size_t)8 * 1024 * 1024;            // 16 MB
  float* q2b = (float*)(bufV + (size_t)8 * 1024 * 1024); // 512 KB
  u16* Ac = (u16*)(q2b + 131072 + 8192);                 // 2 MB

  W6 w6;
  const int widx[6] = {1, 2, 3, 5, 6, 7};  // Wqk_t, Wv_t, Wo_t, Wqk_c, Wv_c, Wo_c
  for (int i = 0; i < 6; ++i) { w6.src[i] = (const float*)d_in[widx[i]]; w6.dst[i] = wb[i]; }
  k_wtrans6<<<dim3(16, 16, 6), 256, 0, stream>>>(w6);

  // ---- token diffusion ----
  k_ln<<<8192, 256, 0, stream>>>(x, ln1w, ln1b, bufA);                           // y1 (bf16)
  k_gemm_nt<<<dim3(64, 8, 2), 256, 0, stream>>>(bufA, wb[0], wb[1], bufQ, bufV, q2b);  // qk+q2, v^T
  k_attn<<<1024, 256, 0, stream>>>(bufQ, bufV, q2b, tau_t, bufA);                // attn_out bf16
  k_gemm_res<<<dim3(64, 8), 256, 0, stream>>>(bufA, wb[2], x, g1, out);          // x1 = x + Wo*g1

  // ---- channel diffusion ----
  k_ln<<<8192, 256, 0, stream>>>(out, ln2w, ln2b, bufQ);                         // y2 (bf16)
  k_gemm_nt<<<dim3(64, 8, 2), 256, 0, stream>>>(bufQ, wb[4], wb[3], bufA, bufV, nullptr); // vc, qkc^T
  k_chan_s<<<64, 256, 0, stream>>>(bufV, tau_c, Ac);                             // softmax matrix
  k_chan_pv<<<dim3(8, 64), 256, 0, stream>>>(bufA, Ac, bufQ);                    // chan attn out bf16
  k_gemm_res<<<dim3(64, 8), 256, 0, stream>>>(bufQ, wb[5], out, g2, out);        // out = x1 + Wo*g2
}